// Round 11
// baseline (225.718 us; speedup 1.0000x reference)
//
#include <hip/hip_runtime.h>
#include <hip/hip_fp16.h>
#include <hip/hip_fp8.h>

// GCN (3 layers) + FC + softmax for N=50000, E=1.6M, H=64, C=10.
// Round 10: FC fused into layer 3 (k_l3fc). Each thread owns one h3
// element and its fcW row (5x 8B nontemporal loads, issued BEFORE the
// gather so the 128MB HBM stream overlaps the L2-bound gather; nt flag
// avoids evicting L2-resident h2s8). h3 buffer + k_logits_part deleted.

constexpr int F1  = 10;   // layer-1 width
constexpr int F1P = 16;   // layer-1 width padded (wave-friendly)
constexpr int HD  = 64;   // hidden width
constexpr int NC  = 10;   // classes

constexpr int BSH   = 7;     // bucket = 128 dst nodes
constexpr int NBC   = 391;   // ceil(50000/128)  (compile-time LDS sizing)
constexpr int BCAPG = 5120;  // global region cap/bucket (mean 4096, +16 sigma)
constexpr int CSTR  = 16;    // cursor stride: one per 64B line
constexpr int LCAP  = 38;    // LDS stage cap/bucket (tile mean 21, +3.7 sigma)
constexpr int TILE  = 8192;  // edges per k_bucket block (512 thr x 16)

static __device__ __forceinline__ float lrelu(float v) {
    return v > 0.0f ? v : 0.01f * v;
}

// fp8 e4m3 decode: hardware builtin if present, else header fallback
#if defined(__has_builtin)
#if __has_builtin(__builtin_amdgcn_cvt_f32_fp8)
#define FP8_DECODE(w, c) __builtin_amdgcn_cvt_f32_fp8((int)(w), (c))
#endif
#endif
#ifndef FP8_DECODE
static __device__ __forceinline__ float fp8_decode_sw(unsigned w, int c) {
    __hip_fp8_e4m3 t; t.__x = (unsigned char)(w >> (8 * c)); return (float)t;
}
#define FP8_DECODE(w, c) fp8_decode_sw((w), (c))
#endif

static __device__ __forceinline__ unsigned char fp8_encode(float v) {
    __hip_fp8_e4m3 t(v);
    return (unsigned char)t.__x;
}

// ---------- CSR build ----------
__global__ void k_bcur(int* __restrict__ bcur, int NB) {
    int b = blockIdx.x * blockDim.x + threadIdx.x;
    if (b < NB) bcur[b * CSTR] = b * BCAPG;
}

// pass 1: LDS-staged binning, wave-coalesced flush
__global__ __launch_bounds__(512) void k_bucket(const int* __restrict__ src,
                                                const int* __restrict__ dst,
                                                int* __restrict__ bcur,
                                                unsigned* __restrict__ bpairs, int E) {
    __shared__ unsigned stage[NBC * LCAP];   // 59.4 KB
    __shared__ int lcnt[NBC];
    for (int i = threadIdx.x; i < NBC; i += 512) lcnt[i] = 0;
    __syncthreads();
    int tile0 = blockIdx.x * TILE;
#pragma unroll
    for (int k = 0; k < TILE / 512; ++k) {
        int e = tile0 + k * 512 + threadIdx.x;
        if (e < E) {
            int d = dst[e];
            unsigned pk = (unsigned)src[e] | ((unsigned)(d & 127) << 16);
            int bb = d >> BSH;
            int pos = atomicAdd(&lcnt[bb], 1);
            if (pos < LCAP) stage[bb * LCAP + pos] = pk;
            else {                                   // rare spill (+3.7 sigma)
                int gp = atomicAdd(&bcur[bb * CSTR], 1);
                bpairs[gp] = pk;
            }
        }
    }
    __syncthreads();
    int wid = threadIdx.x >> 6, lane = threadIdx.x & 63;
    for (int bb = wid; bb < NBC; bb += 8) {
        int cntb = min(lcnt[bb], LCAP);
        if (cntb == 0) continue;
        int gp = 0;
        if (lane == 0) gp = atomicAdd(&bcur[bb * CSTR], cntb);
        gp = __shfl(gp, 0, 64);
        for (int i = lane; i < cntb; i += 64) bpairs[gp + i] = stage[bb * LCAP + i];
    }
}

// pass 2: per bucket: LDS histogram -> scan -> dinv/xs/rowbeg/rowend,
// counting sort -> coalesced uint16 CSR (bucket-padded layout)
__global__ __launch_bounds__(256) void k_fine(const int* __restrict__ bcur,
                                              const unsigned* __restrict__ bpairs,
                                              const float* __restrict__ x,
                                              unsigned short* __restrict__ csr,
                                              float* __restrict__ dinv,
                                              float* __restrict__ xs,
                                              int* __restrict__ rowbeg,
                                              int* __restrict__ rowend, int N) {
    __shared__ unsigned short lout[BCAPG];   // 10 KB
    __shared__ int lcnt[128], lbeg[128];
    int b = blockIdx.x;
    int n0 = b << BSH;
    int nn = min(128, N - n0);
    int base = b * BCAPG;
    int nedges = bcur[b * CSTR] - base;
    for (int i = threadIdx.x; i < nn; i += 256) lcnt[i] = 0;
    __syncthreads();
    for (int i = threadIdx.x; i < nedges; i += 256)
        atomicAdd(&lcnt[(bpairs[base + i] >> 16) & 127], 1);
    __syncthreads();
    if (threadIdx.x == 0) {
        int acc = 0;
        for (int j = 0; j < nn; ++j) { lbeg[j] = acc; acc += lcnt[j]; }
    }
    __syncthreads();
    for (int i = threadIdx.x; i < nn; i += 256) {
        int node = n0 + i;
        float di = rsqrtf(1.0f + (float)lcnt[i]);   // +1 self-loop
        dinv[node]   = di;
        xs[node]     = x[node] * di;
        rowbeg[node] = base + lbeg[i];
        rowend[node] = base + lbeg[i] + lcnt[i];
    }
    __syncthreads();
    for (int i = threadIdx.x; i < nn; i += 256) lcnt[i] = lbeg[i];
    __syncthreads();
    for (int i = threadIdx.x; i < nedges; i += 256) {
        unsigned p = bpairs[base + i];
        int pos = atomicAdd(&lcnt[(p >> 16) & 127], 1);
        lout[pos] = (unsigned short)(p & 0xFFFFu);
    }
    __syncthreads();
    for (int i = threadIdx.x; i < nedges; i += 256) csr[base + i] = lout[i];
}

// ---------- layer 1 fused: gather xs -> h1s = lrelu(s*W1+b1)*dinv (f16) ----------
__global__ void k_l1h1(const int* __restrict__ rowbeg, const int* __restrict__ rowend,
                       const unsigned short* __restrict__ csr,
                       const float* __restrict__ xs, const float* __restrict__ dinv,
                       const float* __restrict__ W1, const float* __restrict__ b1,
                       __half* __restrict__ h1s, int N) {
    int node = (blockIdx.x * blockDim.x + threadIdx.x) >> 6;
    int lane = threadIdx.x & 63;
    if (node >= N) return;
    int lo = rowbeg[node], hi = rowend[node];
    float acc = 0.0f;
    for (int j = lo + lane; j < hi; j += 64) acc += xs[csr[j]];
#pragma unroll
    for (int off = 32; off > 0; off >>= 1) acc += __shfl_xor(acc, off, 64);
    float di = dinv[node];
    float s = di * (acc + xs[node]);           // self-term folded
    if (lane < F1P) {
        float h = (lane < F1) ? lrelu(s * W1[lane] + b1[lane]) * di : 0.0f;
        h1s[node * F1P + lane] = __float2half(h);
    }
}

// ---------- layer 2 fused: wave/node, 8 edges/iter (half2), reg-W2 + LDS-broadcast dot ----------
// lane l: group g=l>>3 owns edge j+g, f2=l&7 owns feature pair 2*f2,2*f2+1
__global__ __launch_bounds__(256, 4) void k_l2h2(const int* __restrict__ rowbeg,
                                                 const int* __restrict__ rowend,
                                                 const unsigned short* __restrict__ csr,
                                                 const __half* __restrict__ h1s,
                                                 const float* __restrict__ dinv,
                                                 const float* __restrict__ W2,
                                                 const float* __restrict__ b2,
                                                 unsigned char* __restrict__ h2s8, int N) {
    __shared__ float awork[4][12];           // per-wave aggregate A[0..9] (+pad)
    int node = (blockIdx.x * blockDim.x + threadIdx.x) >> 6;
    int wid  = threadIdx.x >> 6;
    int lane = threadIdx.x & 63;
    bool valid = node < N;
    // prefetch W2 column (used only at the dot; hides under gather)
    float w2r[F1];
#pragma unroll
    for (int k = 0; k < F1; ++k) w2r[k] = W2[k * HD + lane];
    int g = lane >> 3, f2 = lane & 7;
    int lo = 0, deg = 0;
    if (valid) { lo = rowbeg[node]; deg = rowend[node] - lo; }
    int myidx = (lane < deg) ? (int)csr[lo + lane] : 0;   // whole row, 1 load
    int nfull = min(deg, 64);
    float a0 = 0.0f, a1 = 0.0f;
#pragma unroll
    for (int j = 0; j < 64; j += 8) {
        int e = j + g;
        int sn = __shfl(myidx, e, 64);         // register-only broadcast
        if (e < nfull) {
            __half2 hv = *reinterpret_cast<const __half2*>(h1s + sn * F1P + f2 * 2);
            a0 += __low2float(hv);
            a1 += __high2float(hv);
        }
    }
    for (int j = 64; j < deg; j += 8) {        // tail: deg>64 (not for this graph)
        int e = j + g;
        if (e < deg) {
            int sn = csr[lo + e];
            __half2 hv = *reinterpret_cast<const __half2*>(h1s + sn * F1P + f2 * 2);
            a0 += __low2float(hv);
            a1 += __high2float(hv);
        }
    }
    // reduce across the 8 edge-groups (xor 8,16,32)
    a0 += __shfl_xor(a0, 8, 64); a0 += __shfl_xor(a0, 16, 64); a0 += __shfl_xor(a0, 32, 64);
    a1 += __shfl_xor(a1, 8, 64); a1 += __shfl_xor(a1, 16, 64); a1 += __shfl_xor(a1, 32, 64);
    // self-term
    if (valid) {
        __half2 hs = *reinterpret_cast<const __half2*>(h1s + node * F1P + f2 * 2);
        a0 += __low2float(hs);
        a1 += __high2float(hs);
    }
    if (g == 0 && f2 < 5)                      // lanes 0..4 hold A[0..9]
        *reinterpret_cast<float2*>(&awork[wid][f2 * 2]) = make_float2(a0, a1);
    __syncthreads();
    float4 av0 = *reinterpret_cast<const float4*>(&awork[wid][0]);
    float4 av1 = *reinterpret_cast<const float4*>(&awork[wid][4]);
    float2 av2 = *reinterpret_cast<const float2*>(&awork[wid][8]);
    float S = av0.x * w2r[0] + av0.y * w2r[1] + av0.z * w2r[2] + av0.w * w2r[3]
            + av1.x * w2r[4] + av1.y * w2r[5] + av1.z * w2r[6] + av1.w * w2r[7]
            + av2.x * w2r[8] + av2.y * w2r[9];
    if (valid) {
        float di = dinv[node];
        h2s8[node * HD + lane] = fp8_encode(lrelu(di * S + b2[lane]) * di);
    }
}

// ---------- layer 3 + FC fused: wave/node; gather fp8, reg-W3 dot, then
// each thread multiplies its h3 element by its fcW row (nontemporal) ----------
__global__ __launch_bounds__(256, 3) void k_l3fc(const int* __restrict__ rowbeg,
                                                 const int* __restrict__ rowend,
                                                 const unsigned short* __restrict__ csr,
                                                 const unsigned char* __restrict__ h2s8,
                                                 const float* __restrict__ dinv,
                                                 const float* __restrict__ W3,
                                                 const float* __restrict__ b3,
                                                 const float* __restrict__ fcW,
                                                 float* __restrict__ partial, int N) {
    __shared__ float awork[4][HD];           // per-wave aggregate A[0..63]
    __shared__ float ls[4][NC];
    int node = (blockIdx.x * blockDim.x + threadIdx.x) >> 6;
    int wid  = threadIdx.x >> 6;
    int lane = threadIdx.x & 63;
    bool valid = node < N;
    // prefetch W3 column into registers (coalesced; used only at the dot)
    float w3r[HD];
#pragma unroll
    for (int k = 0; k < HD; ++k) w3r[k] = W3[k * HD + lane];
    // issue the fcW row stream EARLY (nontemporal: don't evict h2s8 from L2);
    // 5x 8B loads, 8B-aligned since (r*10*4) % 8 == 0.
    double fw_d[5];
    if (valid) {
        const double* fw = reinterpret_cast<const double*>(fcW + (size_t)(node * HD + lane) * NC);
#pragma unroll
        for (int c = 0; c < 5; ++c) fw_d[c] = __builtin_nontemporal_load(fw + c);
    } else {
#pragma unroll
        for (int c = 0; c < 5; ++c) fw_d[c] = 0.0;
    }
    int g = lane >> 4, q = lane & 15;
    int lo = 0, deg = 0;
    if (valid) { lo = rowbeg[node]; deg = rowend[node] - lo; }
    int myidx = (lane < deg) ? (int)csr[lo + lane] : 0;   // whole row, 1 load
    int nfull = min(deg, 64);
    float a0 = 0.0f, a1 = 0.0f, a2 = 0.0f, a3 = 0.0f;
#pragma unroll
    for (int j = 0; j < 64; j += 4) {
        int e = j + g;
        int sn = __shfl(myidx, e, 64);         // register-only broadcast
        if (e < nfull) {
            unsigned wv = *reinterpret_cast<const unsigned*>(h2s8 + sn * HD + q * 4);
            a0 += FP8_DECODE(wv, 0);
            a1 += FP8_DECODE(wv, 1);
            a2 += FP8_DECODE(wv, 2);
            a3 += FP8_DECODE(wv, 3);
        }
    }
    for (int j = 64; j < deg; j += 4) {        // tail: deg>64 (not for this graph)
        int e = j + g;
        if (e < deg) {
            int sn = csr[lo + e];
            unsigned wv = *reinterpret_cast<const unsigned*>(h2s8 + sn * HD + q * 4);
            a0 += FP8_DECODE(wv, 0);
            a1 += FP8_DECODE(wv, 1);
            a2 += FP8_DECODE(wv, 2);
            a3 += FP8_DECODE(wv, 3);
        }
    }
    // reduce across the 4 edge-groups (lanes q, q+16, q+32, q+48)
    a0 += __shfl_xor(a0, 16, 64); a0 += __shfl_xor(a0, 32, 64);
    a1 += __shfl_xor(a1, 16, 64); a1 += __shfl_xor(a1, 32, 64);
    a2 += __shfl_xor(a2, 16, 64); a2 += __shfl_xor(a2, 32, 64);
    a3 += __shfl_xor(a3, 16, 64); a3 += __shfl_xor(a3, 32, 64);
    // self-term (identical on all dup lanes)
    if (valid) {
        unsigned ws = *reinterpret_cast<const unsigned*>(h2s8 + node * HD + q * 4);
        a0 += FP8_DECODE(ws, 0);
        a1 += FP8_DECODE(ws, 1);
        a2 += FP8_DECODE(ws, 2);
        a3 += FP8_DECODE(ws, 3);
    }
    if (g == 0)                                // 16 lanes write the 64-float A row
        *reinterpret_cast<float4*>(&awork[wid][q * 4]) = make_float4(a0, a1, a2, a3);
    __syncthreads();
    float S = 0.0f;
#pragma unroll
    for (int c = 0; c < 16; ++c) {             // same-address b128 reads: broadcast
        float4 av = *reinterpret_cast<const float4*>(&awork[wid][c * 4]);
        S += av.x * w3r[4 * c]     + av.y * w3r[4 * c + 1]
           + av.z * w3r[4 * c + 2] + av.w * w3r[4 * c + 3];
    }
    float h = 0.0f;
    if (valid) {
        float di = dinv[node];
        h = lrelu(di * S + b3[lane]);
    }
    // FC: acc[c] = h * fcW[row][c]; reduce over the wave, then over 4 waves
    float acc[NC];
#pragma unroll
    for (int c = 0; c < 5; ++c) {
        float2 f = *reinterpret_cast<float2*>(&fw_d[c]);
        acc[2 * c]     = h * f.x;
        acc[2 * c + 1] = h * f.y;
    }
#pragma unroll
    for (int c = 0; c < NC; ++c) {
        float v = acc[c];
#pragma unroll
        for (int off = 32; off > 0; off >>= 1) v += __shfl_down(v, off, 64);
        acc[c] = v;
    }
    if (lane == 0) {
#pragma unroll
        for (int c = 0; c < NC; ++c) ls[wid][c] = acc[c];
    }
    __syncthreads();
    if (threadIdx.x < NC) {
        float ssum = ls[0][threadIdx.x] + ls[1][threadIdx.x]
                   + ls[2][threadIdx.x] + ls[3][threadIdx.x];
        partial[blockIdx.x * NC + threadIdx.x] = ssum;
    }
}

// reduce per-block partials + bias + softmax, single block (1024 thr)
__global__ __launch_bounds__(1024) void k_final(const float* __restrict__ partial, int nblk,
                                                const float* __restrict__ fcb,
                                                float* __restrict__ out) {
    __shared__ float ls[NC];
    if (threadIdx.x < NC) ls[threadIdx.x] = 0.0f;
    __syncthreads();
    const int NCHUNK = 1024 / NC;            // 102 stripes per class
    int c = threadIdx.x % NC;
    int chunk = threadIdx.x / NC;
    float ssum = 0.0f;
    if (chunk < NCHUNK)
        for (int i = chunk; i < nblk; i += NCHUNK) ssum += partial[i * NC + c];
    if (chunk < NCHUNK) atomicAdd(&ls[c], ssum);
    __syncthreads();
    if (threadIdx.x == 0) {
        float l[NC], m = -1e30f;
        for (int k = 0; k < NC; ++k) { l[k] = ls[k] + fcb[k]; m = fmaxf(m, l[k]); }
        float sum = 0.0f;
        for (int k = 0; k < NC; ++k) { l[k] = expf(l[k] - m); sum += l[k]; }
        float inv = 1.0f / sum;
        for (int k = 0; k < NC; ++k) out[k] = l[k] * inv;
    }
}

extern "C" void kernel_launch(void* const* d_in, const int* in_sizes, int n_in,
                              void* d_out, int out_size, void* d_ws, size_t ws_size,
                              hipStream_t stream) {
    const float* x   = (const float*)d_in[0];
    const int*   ei  = (const int*)d_in[1];
    const float* W1  = (const float*)d_in[2];
    const float* b1  = (const float*)d_in[3];
    const float* W2  = (const float*)d_in[4];
    const float* b2  = (const float*)d_in[5];
    const float* W3  = (const float*)d_in[6];
    const float* b3  = (const float*)d_in[7];
    const float* fcW = (const float*)d_in[8];
    const float* fcb = (const float*)d_in[9];
    float* out = (float*)d_out;

    const int N = in_sizes[0];           // 50000
    const int E = in_sizes[1] / 2;       // 1600000
    const int* src = ei;
    const int* dst = ei + E;
    const int NB = (N + 127) >> BSH;     // 391 buckets

    // workspace carve-up (4B units)
    char* w = (char*)d_ws;
    auto take = [&](size_t elems) { void* p = w; w += elems * 4; return p; };
    float* dinv    = (float*)take(N);
    int*   rowbeg  = (int*)  take(N);
    int*   rowend  = (int*)  take(N);
    int*   bcur    = (int*)  take((size_t)NB * CSTR);
    unsigned short* csr = (unsigned short*)take((size_t)NB * BCAPG / 2); // u16, padded
    float* xs      = (float*)take(N);          // scaled input
    __half* h1s    = (__half*)take((size_t)N * F1P / 2);  // f16, h1*dinv
    unsigned char* h2s8 = (unsigned char*)take((size_t)N * HD / 4);  // fp8, h2*dinv
    float* scratch = (float*)take((size_t)N * HD);        // bpairs / FC partials
    unsigned* bpairs = (unsigned*)scratch;      // CSR build staging (6.4MB < 12.8MB)
    float* partial   = scratch;                 // bpairs dead before k_l3fc

    const int B = 256;
    auto cdiv = [](long long a, long long b) { return (int)((a + b - 1) / b); };

    // CSR build
    k_bcur  <<<cdiv(NB, B), B, 0, stream>>>(bcur, NB);
    k_bucket<<<cdiv(E, TILE), 512, 0, stream>>>(src, dst, bcur, bpairs, E);
    k_fine  <<<NB, 256, 0, stream>>>(bcur, bpairs, x, csr, dinv, xs, rowbeg, rowend, N);

    // fused layers
    k_l1h1<<<cdiv((long long)N * 64, B), B, 0, stream>>>(rowbeg, rowend, csr, xs, dinv, W1, b1, h1s, N);
    k_l2h2<<<cdiv((long long)N * 64, B), B, 0, stream>>>(rowbeg, rowend, csr, h1s, dinv, W2, b2, h2s8, N);
    const int NBLK3 = cdiv((long long)N * 64, B);
    k_l3fc<<<NBLK3, B, 0, stream>>>(rowbeg, rowend, csr, h2s8, dinv, W3, b3, fcW, partial, N);

    // final reduce + softmax
    k_final<<<1, 1024, 0, stream>>>(partial, NBLK3, fcb, out);
}

// Round 12
// 224.311 us; speedup vs baseline: 1.0063x; 1.0063x over previous
//
#include <hip/hip_runtime.h>
#include <hip/hip_fp16.h>
#include <hip/hip_fp8.h>

// GCN (3 layers) + FC + softmax for N=50000, E=1.6M, H=64, C=10.
// Round 11 retry: FC fused into layer 3, but (a) fcW loads issued AFTER
// the gather (vmcnt is in-order; early issue serialized the gather on
// HBM latency), (b) h staged to LDS and fcW read in round-2's layout:
// per-block contiguous 10KB slice, 20 floats/thread = 5 float4 nt loads
// with compile-time class indices, (c) no occupancy cap.

constexpr int F1  = 10;   // layer-1 width
constexpr int F1P = 16;   // layer-1 width padded (wave-friendly)
constexpr int HD  = 64;   // hidden width
constexpr int NC  = 10;   // classes

constexpr int BSH   = 7;     // bucket = 128 dst nodes
constexpr int NBC   = 391;   // ceil(50000/128)  (compile-time LDS sizing)
constexpr int BCAPG = 5120;  // global region cap/bucket (mean 4096, +16 sigma)
constexpr int CSTR  = 16;    // cursor stride: one per 64B line
constexpr int LCAP  = 38;    // LDS stage cap/bucket (tile mean 21, +3.7 sigma)
constexpr int TILE  = 8192;  // edges per k_bucket block (512 thr x 16)

using f32x4 = __attribute__((ext_vector_type(4))) float;

static __device__ __forceinline__ float lrelu(float v) {
    return v > 0.0f ? v : 0.01f * v;
}

// fp8 e4m3 decode: hardware builtin if present, else header fallback
#if defined(__has_builtin)
#if __has_builtin(__builtin_amdgcn_cvt_f32_fp8)
#define FP8_DECODE(w, c) __builtin_amdgcn_cvt_f32_fp8((int)(w), (c))
#endif
#endif
#ifndef FP8_DECODE
static __device__ __forceinline__ float fp8_decode_sw(unsigned w, int c) {
    __hip_fp8_e4m3 t; t.__x = (unsigned char)(w >> (8 * c)); return (float)t;
}
#define FP8_DECODE(w, c) fp8_decode_sw((w), (c))
#endif

static __device__ __forceinline__ unsigned char fp8_encode(float v) {
    __hip_fp8_e4m3 t(v);
    return (unsigned char)t.__x;
}

// ---------- CSR build ----------
__global__ void k_bcur(int* __restrict__ bcur, int NB) {
    int b = blockIdx.x * blockDim.x + threadIdx.x;
    if (b < NB) bcur[b * CSTR] = b * BCAPG;
}

// pass 1: LDS-staged binning, wave-coalesced flush
__global__ __launch_bounds__(512) void k_bucket(const int* __restrict__ src,
                                                const int* __restrict__ dst,
                                                int* __restrict__ bcur,
                                                unsigned* __restrict__ bpairs, int E) {
    __shared__ unsigned stage[NBC * LCAP];   // 59.4 KB
    __shared__ int lcnt[NBC];
    for (int i = threadIdx.x; i < NBC; i += 512) lcnt[i] = 0;
    __syncthreads();
    int tile0 = blockIdx.x * TILE;
#pragma unroll
    for (int k = 0; k < TILE / 512; ++k) {
        int e = tile0 + k * 512 + threadIdx.x;
        if (e < E) {
            int d = dst[e];
            unsigned pk = (unsigned)src[e] | ((unsigned)(d & 127) << 16);
            int bb = d >> BSH;
            int pos = atomicAdd(&lcnt[bb], 1);
            if (pos < LCAP) stage[bb * LCAP + pos] = pk;
            else {                                   // rare spill (+3.7 sigma)
                int gp = atomicAdd(&bcur[bb * CSTR], 1);
                bpairs[gp] = pk;
            }
        }
    }
    __syncthreads();
    int wid = threadIdx.x >> 6, lane = threadIdx.x & 63;
    for (int bb = wid; bb < NBC; bb += 8) {
        int cntb = min(lcnt[bb], LCAP);
        if (cntb == 0) continue;
        int gp = 0;
        if (lane == 0) gp = atomicAdd(&bcur[bb * CSTR], cntb);
        gp = __shfl(gp, 0, 64);
        for (int i = lane; i < cntb; i += 64) bpairs[gp + i] = stage[bb * LCAP + i];
    }
}

// pass 2: per bucket: LDS histogram -> scan -> dinv/xs/rowbeg/rowend,
// counting sort -> coalesced uint16 CSR (bucket-padded layout)
__global__ __launch_bounds__(256) void k_fine(const int* __restrict__ bcur,
                                              const unsigned* __restrict__ bpairs,
                                              const float* __restrict__ x,
                                              unsigned short* __restrict__ csr,
                                              float* __restrict__ dinv,
                                              float* __restrict__ xs,
                                              int* __restrict__ rowbeg,
                                              int* __restrict__ rowend, int N) {
    __shared__ unsigned short lout[BCAPG];   // 10 KB
    __shared__ int lcnt[128], lbeg[128];
    int b = blockIdx.x;
    int n0 = b << BSH;
    int nn = min(128, N - n0);
    int base = b * BCAPG;
    int nedges = bcur[b * CSTR] - base;
    for (int i = threadIdx.x; i < nn; i += 256) lcnt[i] = 0;
    __syncthreads();
    for (int i = threadIdx.x; i < nedges; i += 256)
        atomicAdd(&lcnt[(bpairs[base + i] >> 16) & 127], 1);
    __syncthreads();
    if (threadIdx.x == 0) {
        int acc = 0;
        for (int j = 0; j < nn; ++j) { lbeg[j] = acc; acc += lcnt[j]; }
    }
    __syncthreads();
    for (int i = threadIdx.x; i < nn; i += 256) {
        int node = n0 + i;
        float di = rsqrtf(1.0f + (float)lcnt[i]);   // +1 self-loop
        dinv[node]   = di;
        xs[node]     = x[node] * di;
        rowbeg[node] = base + lbeg[i];
        rowend[node] = base + lbeg[i] + lcnt[i];
    }
    __syncthreads();
    for (int i = threadIdx.x; i < nn; i += 256) lcnt[i] = lbeg[i];
    __syncthreads();
    for (int i = threadIdx.x; i < nedges; i += 256) {
        unsigned p = bpairs[base + i];
        int pos = atomicAdd(&lcnt[(p >> 16) & 127], 1);
        lout[pos] = (unsigned short)(p & 0xFFFFu);
    }
    __syncthreads();
    for (int i = threadIdx.x; i < nedges; i += 256) csr[base + i] = lout[i];
}

// ---------- layer 1 fused: gather xs -> h1s = lrelu(s*W1+b1)*dinv (f16) ----------
__global__ void k_l1h1(const int* __restrict__ rowbeg, const int* __restrict__ rowend,
                       const unsigned short* __restrict__ csr,
                       const float* __restrict__ xs, const float* __restrict__ dinv,
                       const float* __restrict__ W1, const float* __restrict__ b1,
                       __half* __restrict__ h1s, int N) {
    int node = (blockIdx.x * blockDim.x + threadIdx.x) >> 6;
    int lane = threadIdx.x & 63;
    if (node >= N) return;
    int lo = rowbeg[node], hi = rowend[node];
    float acc = 0.0f;
    for (int j = lo + lane; j < hi; j += 64) acc += xs[csr[j]];
#pragma unroll
    for (int off = 32; off > 0; off >>= 1) acc += __shfl_xor(acc, off, 64);
    float di = dinv[node];
    float s = di * (acc + xs[node]);           // self-term folded
    if (lane < F1P) {
        float h = (lane < F1) ? lrelu(s * W1[lane] + b1[lane]) * di : 0.0f;
        h1s[node * F1P + lane] = __float2half(h);
    }
}

// ---------- layer 2 fused: wave/node, 8 edges/iter (half2), reg-W2 + LDS-broadcast dot ----------
// lane l: group g=l>>3 owns edge j+g, f2=l&7 owns feature pair 2*f2,2*f2+1
__global__ __launch_bounds__(256, 4) void k_l2h2(const int* __restrict__ rowbeg,
                                                 const int* __restrict__ rowend,
                                                 const unsigned short* __restrict__ csr,
                                                 const __half* __restrict__ h1s,
                                                 const float* __restrict__ dinv,
                                                 const float* __restrict__ W2,
                                                 const float* __restrict__ b2,
                                                 unsigned char* __restrict__ h2s8, int N) {
    __shared__ float awork[4][12];           // per-wave aggregate A[0..9] (+pad)
    int node = (blockIdx.x * blockDim.x + threadIdx.x) >> 6;
    int wid  = threadIdx.x >> 6;
    int lane = threadIdx.x & 63;
    bool valid = node < N;
    // prefetch W2 column (used only at the dot; hides under gather)
    float w2r[F1];
#pragma unroll
    for (int k = 0; k < F1; ++k) w2r[k] = W2[k * HD + lane];
    int g = lane >> 3, f2 = lane & 7;
    int lo = 0, deg = 0;
    if (valid) { lo = rowbeg[node]; deg = rowend[node] - lo; }
    int myidx = (lane < deg) ? (int)csr[lo + lane] : 0;   // whole row, 1 load
    int nfull = min(deg, 64);
    float a0 = 0.0f, a1 = 0.0f;
#pragma unroll
    for (int j = 0; j < 64; j += 8) {
        int e = j + g;
        int sn = __shfl(myidx, e, 64);         // register-only broadcast
        if (e < nfull) {
            __half2 hv = *reinterpret_cast<const __half2*>(h1s + sn * F1P + f2 * 2);
            a0 += __low2float(hv);
            a1 += __high2float(hv);
        }
    }
    for (int j = 64; j < deg; j += 8) {        // tail: deg>64 (not for this graph)
        int e = j + g;
        if (e < deg) {
            int sn = csr[lo + e];
            __half2 hv = *reinterpret_cast<const __half2*>(h1s + sn * F1P + f2 * 2);
            a0 += __low2float(hv);
            a1 += __high2float(hv);
        }
    }
    // reduce across the 8 edge-groups (xor 8,16,32)
    a0 += __shfl_xor(a0, 8, 64); a0 += __shfl_xor(a0, 16, 64); a0 += __shfl_xor(a0, 32, 64);
    a1 += __shfl_xor(a1, 8, 64); a1 += __shfl_xor(a1, 16, 64); a1 += __shfl_xor(a1, 32, 64);
    // self-term
    if (valid) {
        __half2 hs = *reinterpret_cast<const __half2*>(h1s + node * F1P + f2 * 2);
        a0 += __low2float(hs);
        a1 += __high2float(hs);
    }
    if (g == 0 && f2 < 5)                      // lanes 0..4 hold A[0..9]
        *reinterpret_cast<float2*>(&awork[wid][f2 * 2]) = make_float2(a0, a1);
    __syncthreads();
    float4 av0 = *reinterpret_cast<const float4*>(&awork[wid][0]);
    float4 av1 = *reinterpret_cast<const float4*>(&awork[wid][4]);
    float2 av2 = *reinterpret_cast<const float2*>(&awork[wid][8]);
    float S = av0.x * w2r[0] + av0.y * w2r[1] + av0.z * w2r[2] + av0.w * w2r[3]
            + av1.x * w2r[4] + av1.y * w2r[5] + av1.z * w2r[6] + av1.w * w2r[7]
            + av2.x * w2r[8] + av2.y * w2r[9];
    if (valid) {
        float di = dinv[node];
        h2s8[node * HD + lane] = fp8_encode(lrelu(di * S + b2[lane]) * di);
    }
}

// ---------- layer 3 + FC fused (late-issue, block-contiguous fcW slice) ----------
// Phase A: gather fp8 + reg-W3 dot -> h (per thread).  Phase B: h -> LDS;
// threads 0..127 each take 20 contiguous floats of the block's 10KB fcW
// slice (rows 2t,2t+1 local) = 5 float4 nt loads, compile-time classes.
__global__ __launch_bounds__(256) void k_l3fc(const int* __restrict__ rowbeg,
                                              const int* __restrict__ rowend,
                                              const unsigned short* __restrict__ csr,
                                              const unsigned char* __restrict__ h2s8,
                                              const float* __restrict__ dinv,
                                              const float* __restrict__ W3,
                                              const float* __restrict__ b3,
                                              const float* __restrict__ fcW,
                                              float* __restrict__ partial, int N) {
    __shared__ float awork[4][HD];           // per-wave aggregate A[0..63]
    __shared__ float h_lds[256];
    __shared__ float ls[2][NC];
    int node = (blockIdx.x * blockDim.x + threadIdx.x) >> 6;
    int wid  = threadIdx.x >> 6;
    int lane = threadIdx.x & 63;
    bool valid = node < N;
    // prefetch W3 column into registers (coalesced; used only at the dot)
    float w3r[HD];
#pragma unroll
    for (int k = 0; k < HD; ++k) w3r[k] = W3[k * HD + lane];
    int g = lane >> 4, q = lane & 15;
    int lo = 0, deg = 0;
    if (valid) { lo = rowbeg[node]; deg = rowend[node] - lo; }
    int myidx = (lane < deg) ? (int)csr[lo + lane] : 0;   // whole row, 1 load
    int nfull = min(deg, 64);
    float a0 = 0.0f, a1 = 0.0f, a2 = 0.0f, a3 = 0.0f;
#pragma unroll
    for (int j = 0; j < 64; j += 4) {
        int e = j + g;
        int sn = __shfl(myidx, e, 64);         // register-only broadcast
        if (e < nfull) {
            unsigned wv = *reinterpret_cast<const unsigned*>(h2s8 + sn * HD + q * 4);
            a0 += FP8_DECODE(wv, 0);
            a1 += FP8_DECODE(wv, 1);
            a2 += FP8_DECODE(wv, 2);
            a3 += FP8_DECODE(wv, 3);
        }
    }
    for (int j = 64; j < deg; j += 4) {        // tail: deg>64 (not for this graph)
        int e = j + g;
        if (e < deg) {
            int sn = csr[lo + e];
            unsigned wv = *reinterpret_cast<const unsigned*>(h2s8 + sn * HD + q * 4);
            a0 += FP8_DECODE(wv, 0);
            a1 += FP8_DECODE(wv, 1);
            a2 += FP8_DECODE(wv, 2);
            a3 += FP8_DECODE(wv, 3);
        }
    }
    // reduce across the 4 edge-groups (lanes q, q+16, q+32, q+48)
    a0 += __shfl_xor(a0, 16, 64); a0 += __shfl_xor(a0, 32, 64);
    a1 += __shfl_xor(a1, 16, 64); a1 += __shfl_xor(a1, 32, 64);
    a2 += __shfl_xor(a2, 16, 64); a2 += __shfl_xor(a2, 32, 64);
    a3 += __shfl_xor(a3, 16, 64); a3 += __shfl_xor(a3, 32, 64);
    // self-term (identical on all dup lanes)
    if (valid) {
        unsigned ws = *reinterpret_cast<const unsigned*>(h2s8 + node * HD + q * 4);
        a0 += FP8_DECODE(ws, 0);
        a1 += FP8_DECODE(ws, 1);
        a2 += FP8_DECODE(ws, 2);
        a3 += FP8_DECODE(ws, 3);
    }
    if (g == 0)                                // 16 lanes write the 64-float A row
        *reinterpret_cast<float4*>(&awork[wid][q * 4]) = make_float4(a0, a1, a2, a3);
    __syncthreads();
    float S = 0.0f;
#pragma unroll
    for (int c = 0; c < 16; ++c) {             // same-address b128 reads: broadcast
        float4 av = *reinterpret_cast<const float4*>(&awork[wid][c * 4]);
        S += av.x * w3r[4 * c]     + av.y * w3r[4 * c + 1]
           + av.z * w3r[4 * c + 2] + av.w * w3r[4 * c + 3];
    }
    float h = 0.0f;
    if (valid) {
        float di = dinv[node];
        h = lrelu(di * S + b3[lane]);
    }
    h_lds[threadIdx.x] = h;
    __syncthreads();
    // Phase B: FC on the block's contiguous fcW slice (issued LATE).
    float acc[NC];
#pragma unroll
    for (int c = 0; c < NC; ++c) acc[c] = 0.0f;
    int t = threadIdx.x;
    if (t < 128) {
        size_t row0 = (size_t)blockIdx.x * 256 + 2 * t;      // global fcW row
        if (row0 + 1 < (size_t)N * HD) {
            const f32x4* wp = reinterpret_cast<const f32x4*>(fcW + row0 * NC);
            f32x4 w0 = __builtin_nontemporal_load(wp + 0);
            f32x4 w1 = __builtin_nontemporal_load(wp + 1);
            f32x4 w2 = __builtin_nontemporal_load(wp + 2);
            f32x4 w3 = __builtin_nontemporal_load(wp + 3);
            f32x4 w4 = __builtin_nontemporal_load(wp + 4);
            float hv0 = h_lds[2 * t], hv1 = h_lds[2 * t + 1];
            acc[0] += hv0 * w0.x; acc[1] += hv0 * w0.y; acc[2] += hv0 * w0.z; acc[3] += hv0 * w0.w;
            acc[4] += hv0 * w1.x; acc[5] += hv0 * w1.y; acc[6] += hv0 * w1.z; acc[7] += hv0 * w1.w;
            acc[8] += hv0 * w2.x; acc[9] += hv0 * w2.y; acc[0] += hv1 * w2.z; acc[1] += hv1 * w2.w;
            acc[2] += hv1 * w3.x; acc[3] += hv1 * w3.y; acc[4] += hv1 * w3.z; acc[5] += hv1 * w3.w;
            acc[6] += hv1 * w4.x; acc[7] += hv1 * w4.y; acc[8] += hv1 * w4.z; acc[9] += hv1 * w4.w;
        }
    }
#pragma unroll
    for (int c = 0; c < NC; ++c) {
        float v = acc[c];
#pragma unroll
        for (int off = 32; off > 0; off >>= 1) v += __shfl_down(v, off, 64);
        acc[c] = v;
    }
    if (lane == 0 && wid < 2) {
#pragma unroll
        for (int c = 0; c < NC; ++c) ls[wid][c] = acc[c];
    }
    __syncthreads();
    if (t < NC) partial[blockIdx.x * NC + t] = ls[0][t] + ls[1][t];
}

// reduce per-block partials + bias + softmax, single block (1024 thr)
__global__ __launch_bounds__(1024) void k_final(const float* __restrict__ partial, int nblk,
                                                const float* __restrict__ fcb,
                                                float* __restrict__ out) {
    __shared__ float ls[NC];
    if (threadIdx.x < NC) ls[threadIdx.x] = 0.0f;
    __syncthreads();
    const int NCHUNK = 1024 / NC;            // 102 stripes per class
    int c = threadIdx.x % NC;
    int chunk = threadIdx.x / NC;
    float ssum = 0.0f;
    if (chunk < NCHUNK)
        for (int i = chunk; i < nblk; i += NCHUNK) ssum += partial[i * NC + c];
    if (chunk < NCHUNK) atomicAdd(&ls[c], ssum);
    __syncthreads();
    if (threadIdx.x == 0) {
        float l[NC], m = -1e30f;
        for (int k = 0; k < NC; ++k) { l[k] = ls[k] + fcb[k]; m = fmaxf(m, l[k]); }
        float sum = 0.0f;
        for (int k = 0; k < NC; ++k) { l[k] = expf(l[k] - m); sum += l[k]; }
        float inv = 1.0f / sum;
        for (int k = 0; k < NC; ++k) out[k] = l[k] * inv;
    }
}

extern "C" void kernel_launch(void* const* d_in, const int* in_sizes, int n_in,
                              void* d_out, int out_size, void* d_ws, size_t ws_size,
                              hipStream_t stream) {
    const float* x   = (const float*)d_in[0];
    const int*   ei  = (const int*)d_in[1];
    const float* W1  = (const float*)d_in[2];
    const float* b1  = (const float*)d_in[3];
    const float* W2  = (const float*)d_in[4];
    const float* b2  = (const float*)d_in[5];
    const float* W3  = (const float*)d_in[6];
    const float* b3  = (const float*)d_in[7];
    const float* fcW = (const float*)d_in[8];
    const float* fcb = (const float*)d_in[9];
    float* out = (float*)d_out;

    const int N = in_sizes[0];           // 50000
    const int E = in_sizes[1] / 2;       // 1600000
    const int* src = ei;
    const int* dst = ei + E;
    const int NB = (N + 127) >> BSH;     // 391 buckets

    // workspace carve-up (4B units)
    char* w = (char*)d_ws;
    auto take = [&](size_t elems) { void* p = w; w += elems * 4; return p; };
    float* dinv    = (float*)take(N);
    int*   rowbeg  = (int*)  take(N);
    int*   rowend  = (int*)  take(N);
    int*   bcur    = (int*)  take((size_t)NB * CSTR);
    unsigned short* csr = (unsigned short*)take((size_t)NB * BCAPG / 2); // u16, padded
    float* xs      = (float*)take(N);          // scaled input
    __half* h1s    = (__half*)take((size_t)N * F1P / 2);  // f16, h1*dinv
    unsigned char* h2s8 = (unsigned char*)take((size_t)N * HD / 4);  // fp8, h2*dinv
    float* scratch = (float*)take((size_t)N * HD);        // bpairs / FC partials
    unsigned* bpairs = (unsigned*)scratch;      // CSR build staging (6.4MB < 12.8MB)
    float* partial   = scratch;                 // bpairs dead before k_l3fc

    const int B = 256;
    auto cdiv = [](long long a, long long b) { return (int)((a + b - 1) / b); };

    // CSR build
    k_bcur  <<<cdiv(NB, B), B, 0, stream>>>(bcur, NB);
    k_bucket<<<cdiv(E, TILE), 512, 0, stream>>>(src, dst, bcur, bpairs, E);
    k_fine  <<<NB, 256, 0, stream>>>(bcur, bpairs, x, csr, dinv, xs, rowbeg, rowend, N);

    // fused layers
    k_l1h1<<<cdiv((long long)N * 64, B), B, 0, stream>>>(rowbeg, rowend, csr, xs, dinv, W1, b1, h1s, N);
    k_l2h2<<<cdiv((long long)N * 64, B), B, 0, stream>>>(rowbeg, rowend, csr, h1s, dinv, W2, b2, h2s8, N);
    const int NBLK3 = cdiv((long long)N * 64, B);
    k_l3fc<<<NBLK3, B, 0, stream>>>(rowbeg, rowend, csr, h2s8, dinv, W3, b3, fcW, partial, N);

    // final reduce + softmax
    k_final<<<1, 1024, 0, stream>>>(partial, NBLK3, fcb, out);
}

// Round 13
// 179.700 us; speedup vs baseline: 1.2561x; 1.2483x over previous
//
#include <hip/hip_runtime.h>
#include <hip/hip_fp16.h>
#include <hip/hip_fp8.h>

// GCN (3 layers) + FC + softmax for N=50000, E=1.6M, H=64, C=10.
// Round 12: REVERT to round-10 split pipeline (fusion lost ~35us twice:
// gather wants occupancy, FC stream wants none; split lets each run at
// its own best config). Plus: wave-uniform early-break in gather loops
// (nfull is wave-uniform -> scalar branch skips predicated-off iters),
// and k_final widened to 1024 threads.

constexpr int F1  = 10;   // layer-1 width
constexpr int F1P = 16;   // layer-1 width padded (wave-friendly)
constexpr int HD  = 64;   // hidden width
constexpr int NC  = 10;   // classes
constexpr int LOGIT_BLOCKS = 2048;

constexpr int BSH   = 7;     // bucket = 128 dst nodes
constexpr int NBC   = 391;   // ceil(50000/128)  (compile-time LDS sizing)
constexpr int BCAPG = 5120;  // global region cap/bucket (mean 4096, +16 sigma)
constexpr int CSTR  = 16;    // cursor stride: one per 64B line
constexpr int LCAP  = 38;    // LDS stage cap/bucket (tile mean 21, +3.7 sigma)
constexpr int TILE  = 8192;  // edges per k_bucket block (512 thr x 16)

static __device__ __forceinline__ float lrelu(float v) {
    return v > 0.0f ? v : 0.01f * v;
}

// fp8 e4m3 decode: hardware builtin if present, else header fallback
#if defined(__has_builtin)
#if __has_builtin(__builtin_amdgcn_cvt_f32_fp8)
#define FP8_DECODE(w, c) __builtin_amdgcn_cvt_f32_fp8((int)(w), (c))
#endif
#endif
#ifndef FP8_DECODE
static __device__ __forceinline__ float fp8_decode_sw(unsigned w, int c) {
    __hip_fp8_e4m3 t; t.__x = (unsigned char)(w >> (8 * c)); return (float)t;
}
#define FP8_DECODE(w, c) fp8_decode_sw((w), (c))
#endif

static __device__ __forceinline__ unsigned char fp8_encode(float v) {
    __hip_fp8_e4m3 t(v);
    return (unsigned char)t.__x;
}

// ---------- CSR build ----------
__global__ void k_bcur(int* __restrict__ bcur, int NB) {
    int b = blockIdx.x * blockDim.x + threadIdx.x;
    if (b < NB) bcur[b * CSTR] = b * BCAPG;
}

// pass 1: LDS-staged binning, wave-coalesced flush
__global__ __launch_bounds__(512) void k_bucket(const int* __restrict__ src,
                                                const int* __restrict__ dst,
                                                int* __restrict__ bcur,
                                                unsigned* __restrict__ bpairs, int E) {
    __shared__ unsigned stage[NBC * LCAP];   // 59.4 KB
    __shared__ int lcnt[NBC];
    for (int i = threadIdx.x; i < NBC; i += 512) lcnt[i] = 0;
    __syncthreads();
    int tile0 = blockIdx.x * TILE;
#pragma unroll
    for (int k = 0; k < TILE / 512; ++k) {
        int e = tile0 + k * 512 + threadIdx.x;
        if (e < E) {
            int d = dst[e];
            unsigned pk = (unsigned)src[e] | ((unsigned)(d & 127) << 16);
            int bb = d >> BSH;
            int pos = atomicAdd(&lcnt[bb], 1);
            if (pos < LCAP) stage[bb * LCAP + pos] = pk;
            else {                                   // rare spill (+3.7 sigma)
                int gp = atomicAdd(&bcur[bb * CSTR], 1);
                bpairs[gp] = pk;
            }
        }
    }
    __syncthreads();
    int wid = threadIdx.x >> 6, lane = threadIdx.x & 63;
    for (int bb = wid; bb < NBC; bb += 8) {
        int cntb = min(lcnt[bb], LCAP);
        if (cntb == 0) continue;
        int gp = 0;
        if (lane == 0) gp = atomicAdd(&bcur[bb * CSTR], cntb);
        gp = __shfl(gp, 0, 64);
        for (int i = lane; i < cntb; i += 64) bpairs[gp + i] = stage[bb * LCAP + i];
    }
}

// pass 2: per bucket: LDS histogram -> scan -> dinv/xs/rowbeg/rowend,
// counting sort -> coalesced uint16 CSR (bucket-padded layout)
__global__ __launch_bounds__(256) void k_fine(const int* __restrict__ bcur,
                                              const unsigned* __restrict__ bpairs,
                                              const float* __restrict__ x,
                                              unsigned short* __restrict__ csr,
                                              float* __restrict__ dinv,
                                              float* __restrict__ xs,
                                              int* __restrict__ rowbeg,
                                              int* __restrict__ rowend, int N) {
    __shared__ unsigned short lout[BCAPG];   // 10 KB
    __shared__ int lcnt[128], lbeg[128];
    int b = blockIdx.x;
    int n0 = b << BSH;
    int nn = min(128, N - n0);
    int base = b * BCAPG;
    int nedges = bcur[b * CSTR] - base;
    for (int i = threadIdx.x; i < nn; i += 256) lcnt[i] = 0;
    __syncthreads();
    for (int i = threadIdx.x; i < nedges; i += 256)
        atomicAdd(&lcnt[(bpairs[base + i] >> 16) & 127], 1);
    __syncthreads();
    if (threadIdx.x == 0) {
        int acc = 0;
        for (int j = 0; j < nn; ++j) { lbeg[j] = acc; acc += lcnt[j]; }
    }
    __syncthreads();
    for (int i = threadIdx.x; i < nn; i += 256) {
        int node = n0 + i;
        float di = rsqrtf(1.0f + (float)lcnt[i]);   // +1 self-loop
        dinv[node]   = di;
        xs[node]     = x[node] * di;
        rowbeg[node] = base + lbeg[i];
        rowend[node] = base + lbeg[i] + lcnt[i];
    }
    __syncthreads();
    for (int i = threadIdx.x; i < nn; i += 256) lcnt[i] = lbeg[i];
    __syncthreads();
    for (int i = threadIdx.x; i < nedges; i += 256) {
        unsigned p = bpairs[base + i];
        int pos = atomicAdd(&lcnt[(p >> 16) & 127], 1);
        lout[pos] = (unsigned short)(p & 0xFFFFu);
    }
    __syncthreads();
    for (int i = threadIdx.x; i < nedges; i += 256) csr[base + i] = lout[i];
}

// ---------- layer 1 fused: gather xs -> h1s = lrelu(s*W1+b1)*dinv (f16) ----------
__global__ void k_l1h1(const int* __restrict__ rowbeg, const int* __restrict__ rowend,
                       const unsigned short* __restrict__ csr,
                       const float* __restrict__ xs, const float* __restrict__ dinv,
                       const float* __restrict__ W1, const float* __restrict__ b1,
                       __half* __restrict__ h1s, int N) {
    int node = (blockIdx.x * blockDim.x + threadIdx.x) >> 6;
    int lane = threadIdx.x & 63;
    if (node >= N) return;
    int lo = rowbeg[node], hi = rowend[node];
    float acc = 0.0f;
    for (int j = lo + lane; j < hi; j += 64) acc += xs[csr[j]];
#pragma unroll
    for (int off = 32; off > 0; off >>= 1) acc += __shfl_xor(acc, off, 64);
    float di = dinv[node];
    float s = di * (acc + xs[node]);           // self-term folded
    if (lane < F1P) {
        float h = (lane < F1) ? lrelu(s * W1[lane] + b1[lane]) * di : 0.0f;
        h1s[node * F1P + lane] = __float2half(h);
    }
}

// ---------- layer 2 fused: wave/node, 8 edges/iter (half2), reg-W2 + LDS-broadcast dot ----------
// lane l: group g=l>>3 owns edge j+g, f2=l&7 owns feature pair 2*f2,2*f2+1
__global__ __launch_bounds__(256, 4) void k_l2h2(const int* __restrict__ rowbeg,
                                                 const int* __restrict__ rowend,
                                                 const unsigned short* __restrict__ csr,
                                                 const __half* __restrict__ h1s,
                                                 const float* __restrict__ dinv,
                                                 const float* __restrict__ W2,
                                                 const float* __restrict__ b2,
                                                 unsigned char* __restrict__ h2s8, int N) {
    __shared__ float awork[4][12];           // per-wave aggregate A[0..9] (+pad)
    int node = (blockIdx.x * blockDim.x + threadIdx.x) >> 6;
    int wid  = threadIdx.x >> 6;
    int lane = threadIdx.x & 63;
    bool valid = node < N;
    // prefetch W2 column (used only at the dot; hides under gather)
    float w2r[F1];
#pragma unroll
    for (int k = 0; k < F1; ++k) w2r[k] = W2[k * HD + lane];
    int g = lane >> 3, f2 = lane & 7;
    int lo = 0, deg = 0;
    if (valid) { lo = rowbeg[node]; deg = rowend[node] - lo; }
    int myidx = (lane < deg) ? (int)csr[lo + lane] : 0;   // whole row, 1 load
    int nfull = min(deg, 64);
    float a0 = 0.0f, a1 = 0.0f;
#pragma unroll
    for (int j = 0; j < 64; j += 8) {
        if (j >= nfull) break;                 // wave-uniform: skip dead iters
        int e = j + g;
        int sn = __shfl(myidx, e, 64);         // register-only broadcast
        if (e < nfull) {
            __half2 hv = *reinterpret_cast<const __half2*>(h1s + sn * F1P + f2 * 2);
            a0 += __low2float(hv);
            a1 += __high2float(hv);
        }
    }
    for (int j = 64; j < deg; j += 8) {        // tail: deg>64 (not for this graph)
        int e = j + g;
        if (e < deg) {
            int sn = csr[lo + e];
            __half2 hv = *reinterpret_cast<const __half2*>(h1s + sn * F1P + f2 * 2);
            a0 += __low2float(hv);
            a1 += __high2float(hv);
        }
    }
    // reduce across the 8 edge-groups (xor 8,16,32)
    a0 += __shfl_xor(a0, 8, 64); a0 += __shfl_xor(a0, 16, 64); a0 += __shfl_xor(a0, 32, 64);
    a1 += __shfl_xor(a1, 8, 64); a1 += __shfl_xor(a1, 16, 64); a1 += __shfl_xor(a1, 32, 64);
    // self-term
    if (valid) {
        __half2 hs = *reinterpret_cast<const __half2*>(h1s + node * F1P + f2 * 2);
        a0 += __low2float(hs);
        a1 += __high2float(hs);
    }
    if (g == 0 && f2 < 5)                      // lanes 0..4 hold A[0..9]
        *reinterpret_cast<float2*>(&awork[wid][f2 * 2]) = make_float2(a0, a1);
    __syncthreads();
    float4 av0 = *reinterpret_cast<const float4*>(&awork[wid][0]);
    float4 av1 = *reinterpret_cast<const float4*>(&awork[wid][4]);
    float2 av2 = *reinterpret_cast<const float2*>(&awork[wid][8]);
    float S = av0.x * w2r[0] + av0.y * w2r[1] + av0.z * w2r[2] + av0.w * w2r[3]
            + av1.x * w2r[4] + av1.y * w2r[5] + av1.z * w2r[6] + av1.w * w2r[7]
            + av2.x * w2r[8] + av2.y * w2r[9];
    if (valid) {
        float di = dinv[node];
        h2s8[node * HD + lane] = fp8_encode(lrelu(di * S + b2[lane]) * di);
    }
}

// ---------- layer 3 fused: wave/node, 4 edges/iter (uchar4 fp8), reg-W3 + LDS-broadcast dot ----------
// lane l: group g=l>>4 owns edge j+g, q=l&15 owns features q*4..q*4+3.
__global__ __launch_bounds__(256, 4) void k_l3h3(const int* __restrict__ rowbeg,
                                                 const int* __restrict__ rowend,
                                                 const unsigned short* __restrict__ csr,
                                                 const unsigned char* __restrict__ h2s8,
                                                 const float* __restrict__ dinv,
                                                 const float* __restrict__ W3,
                                                 const float* __restrict__ b3,
                                                 float* __restrict__ h3, int N) {
    __shared__ float awork[4][HD];           // per-wave aggregate A[0..63]
    int node = (blockIdx.x * blockDim.x + threadIdx.x) >> 6;
    int wid  = threadIdx.x >> 6;
    int lane = threadIdx.x & 63;
    bool valid = node < N;
    // prefetch W3 column into registers (coalesced; used only at the dot)
    float w3r[HD];
#pragma unroll
    for (int k = 0; k < HD; ++k) w3r[k] = W3[k * HD + lane];
    int g = lane >> 4, q = lane & 15;
    int lo = 0, deg = 0;
    if (valid) { lo = rowbeg[node]; deg = rowend[node] - lo; }
    int myidx = (lane < deg) ? (int)csr[lo + lane] : 0;   // whole row, 1 load
    int nfull = min(deg, 64);
    float a0 = 0.0f, a1 = 0.0f, a2 = 0.0f, a3 = 0.0f;
#pragma unroll
    for (int j = 0; j < 64; j += 4) {
        if (j >= nfull) break;                 // wave-uniform: skip dead iters
        int e = j + g;
        int sn = __shfl(myidx, e, 64);         // register-only broadcast
        if (e < nfull) {
            unsigned wv = *reinterpret_cast<const unsigned*>(h2s8 + sn * HD + q * 4);
            a0 += FP8_DECODE(wv, 0);
            a1 += FP8_DECODE(wv, 1);
            a2 += FP8_DECODE(wv, 2);
            a3 += FP8_DECODE(wv, 3);
        }
    }
    for (int j = 64; j < deg; j += 4) {        // tail: deg>64 (not for this graph)
        int e = j + g;
        if (e < deg) {
            int sn = csr[lo + e];
            unsigned wv = *reinterpret_cast<const unsigned*>(h2s8 + sn * HD + q * 4);
            a0 += FP8_DECODE(wv, 0);
            a1 += FP8_DECODE(wv, 1);
            a2 += FP8_DECODE(wv, 2);
            a3 += FP8_DECODE(wv, 3);
        }
    }
    // reduce across the 4 edge-groups (lanes q, q+16, q+32, q+48)
    a0 += __shfl_xor(a0, 16, 64); a0 += __shfl_xor(a0, 32, 64);
    a1 += __shfl_xor(a1, 16, 64); a1 += __shfl_xor(a1, 32, 64);
    a2 += __shfl_xor(a2, 16, 64); a2 += __shfl_xor(a2, 32, 64);
    a3 += __shfl_xor(a3, 16, 64); a3 += __shfl_xor(a3, 32, 64);
    // self-term (identical on all dup lanes)
    if (valid) {
        unsigned ws = *reinterpret_cast<const unsigned*>(h2s8 + node * HD + q * 4);
        a0 += FP8_DECODE(ws, 0);
        a1 += FP8_DECODE(ws, 1);
        a2 += FP8_DECODE(ws, 2);
        a3 += FP8_DECODE(ws, 3);
    }
    if (g == 0)                                // 16 lanes write the 64-float A row
        *reinterpret_cast<float4*>(&awork[wid][q * 4]) = make_float4(a0, a1, a2, a3);
    __syncthreads();
    float S = 0.0f;
#pragma unroll
    for (int c = 0; c < 16; ++c) {             // same-address b128 reads: broadcast
        float4 av = *reinterpret_cast<const float4*>(&awork[wid][c * 4]);
        S += av.x * w3r[4 * c]     + av.y * w3r[4 * c + 1]
           + av.z * w3r[4 * c + 2] + av.w * w3r[4 * c + 3];
    }
    if (valid) {
        float di = dinv[node];
        h3[node * HD + lane] = lrelu(di * S + b3[lane]);
    }
}

// ---------- FC partial: 2 rows = 5 float4s per thread, compile-time classes ----------
__global__ void k_logits_part(const float* __restrict__ h3,
                              const float4* __restrict__ fw4,
                              float* __restrict__ partial, int P /*row pairs*/) {
    float acc[NC];
#pragma unroll
    for (int c = 0; c < NC; ++c) acc[c] = 0.0f;
    int nth = gridDim.x * blockDim.x;
    for (int p = blockIdx.x * blockDim.x + threadIdx.x; p < P; p += nth) {
        const float4* w = fw4 + (size_t)p * 5;
        float4 w0 = w[0], w1 = w[1], w2 = w[2], w3 = w[3], w4 = w[4];
        float2 hv = *reinterpret_cast<const float2*>(h3 + 2 * (size_t)p);
        acc[0] += hv.x * w0.x; acc[1] += hv.x * w0.y; acc[2] += hv.x * w0.z; acc[3] += hv.x * w0.w;
        acc[4] += hv.x * w1.x; acc[5] += hv.x * w1.y; acc[6] += hv.x * w1.z; acc[7] += hv.x * w1.w;
        acc[8] += hv.x * w2.x; acc[9] += hv.x * w2.y; acc[0] += hv.y * w2.z; acc[1] += hv.y * w2.w;
        acc[2] += hv.y * w3.x; acc[3] += hv.y * w3.y; acc[4] += hv.y * w3.z; acc[5] += hv.y * w3.w;
        acc[6] += hv.y * w4.x; acc[7] += hv.y * w4.y; acc[8] += hv.y * w4.z; acc[9] += hv.y * w4.w;
    }
#pragma unroll
    for (int c = 0; c < NC; ++c) {
        float v = acc[c];
#pragma unroll
        for (int off = 32; off > 0; off >>= 1) v += __shfl_down(v, off, 64);
        acc[c] = v;
    }
    __shared__ float ls[4][NC];
    int wid = threadIdx.x >> 6, lane = threadIdx.x & 63;
    if (lane == 0) {
#pragma unroll
        for (int c = 0; c < NC; ++c) ls[wid][c] = acc[c];
    }
    __syncthreads();
    if (threadIdx.x < NC) {
        float ssum = ls[0][threadIdx.x] + ls[1][threadIdx.x]
                   + ls[2][threadIdx.x] + ls[3][threadIdx.x];
        partial[blockIdx.x * NC + threadIdx.x] = ssum;
    }
}

// reduce per-block partials + bias + softmax, single block (1024 thr)
__global__ __launch_bounds__(1024) void k_final(const float* __restrict__ partial, int nblk,
                                                const float* __restrict__ fcb,
                                                float* __restrict__ out) {
    __shared__ float ls[NC];
    if (threadIdx.x < NC) ls[threadIdx.x] = 0.0f;
    __syncthreads();
    const int NCHUNK = 1024 / NC;            // 102 stripes per class
    int c = threadIdx.x % NC;
    int chunk = threadIdx.x / NC;
    float ssum = 0.0f;
    if (chunk < NCHUNK)
        for (int i = chunk; i < nblk; i += NCHUNK) ssum += partial[i * NC + c];
    if (chunk < NCHUNK) atomicAdd(&ls[c], ssum);
    __syncthreads();
    if (threadIdx.x == 0) {
        float l[NC], m = -1e30f;
        for (int k = 0; k < NC; ++k) { l[k] = ls[k] + fcb[k]; m = fmaxf(m, l[k]); }
        float sum = 0.0f;
        for (int k = 0; k < NC; ++k) { l[k] = expf(l[k] - m); sum += l[k]; }
        float inv = 1.0f / sum;
        for (int k = 0; k < NC; ++k) out[k] = l[k] * inv;
    }
}

extern "C" void kernel_launch(void* const* d_in, const int* in_sizes, int n_in,
                              void* d_out, int out_size, void* d_ws, size_t ws_size,
                              hipStream_t stream) {
    const float* x   = (const float*)d_in[0];
    const int*   ei  = (const int*)d_in[1];
    const float* W1  = (const float*)d_in[2];
    const float* b1  = (const float*)d_in[3];
    const float* W2  = (const float*)d_in[4];
    const float* b2  = (const float*)d_in[5];
    const float* W3  = (const float*)d_in[6];
    const float* b3  = (const float*)d_in[7];
    const float* fcW = (const float*)d_in[8];
    const float* fcb = (const float*)d_in[9];
    float* out = (float*)d_out;

    const int N = in_sizes[0];           // 50000
    const int E = in_sizes[1] / 2;       // 1600000
    const int* src = ei;
    const int* dst = ei + E;
    const int NB = (N + 127) >> BSH;     // 391 buckets

    // workspace carve-up (4B units)
    char* w = (char*)d_ws;
    auto take = [&](size_t elems) { void* p = w; w += elems * 4; return p; };
    float* dinv    = (float*)take(N);
    int*   rowbeg  = (int*)  take(N);
    int*   rowend  = (int*)  take(N);
    int*   bcur    = (int*)  take((size_t)NB * CSTR);
    unsigned short* csr = (unsigned short*)take((size_t)NB * BCAPG / 2); // u16, padded
    float* xs      = (float*)take(N);          // scaled input; FC partials later
    __half* h1s    = (__half*)take((size_t)N * F1P / 2);  // f16, h1*dinv
    unsigned char* h2s8 = (unsigned char*)take((size_t)N * HD / 4);  // fp8, h2*dinv
    float* h3      = (float*)take((size_t)N * HD);
    float* partial = xs;                        // xs dead after k_l1h1
    unsigned* bpairs = (unsigned*)h3;           // h3 not live during CSR build (8MB<12.8MB)

    const int B = 256;
    auto cdiv = [](long long a, long long b) { return (int)((a + b - 1) / b); };

    // CSR build
    k_bcur  <<<cdiv(NB, B), B, 0, stream>>>(bcur, NB);
    k_bucket<<<cdiv(E, TILE), 512, 0, stream>>>(src, dst, bcur, bpairs, E);
    k_fine  <<<NB, 256, 0, stream>>>(bcur, bpairs, x, csr, dinv, xs, rowbeg, rowend, N);

    // fused layers
    k_l1h1<<<cdiv((long long)N * 64, B), B, 0, stream>>>(rowbeg, rowend, csr, xs, dinv, W1, b1, h1s, N);
    k_l2h2<<<cdiv((long long)N * 64, B), B, 0, stream>>>(rowbeg, rowend, csr, h1s, dinv, W2, b2, h2s8, N);
    k_l3h3<<<cdiv((long long)N * 64, B), B, 0, stream>>>(rowbeg, rowend, csr, h2s8, dinv, W3, b3, h3, N);

    // FC + softmax
    const int P = (N * HD) / 2;
    k_logits_part<<<LOGIT_BLOCKS, B, 0, stream>>>(h3, (const float4*)fcW, partial, P);
    k_final<<<1, 1024, 0, stream>>>(partial, LOGIT_BLOCKS, fcb, out);
}

// Round 14
// 170.488 us; speedup vs baseline: 1.3240x; 1.0540x over previous
//
#include <hip/hip_runtime.h>
#include <hip/hip_fp16.h>
#include <hip/hip_fp8.h>

// GCN (3 layers) + FC + softmax for N=50000, E=1.6M, H=64, C=10.
// Round 13: (1) k_l3h3 W3 k-sharded across the 4 waves (16 regs/lane
// instead of 64 -> 8 waves/SIMD occupancy for the latency-bound gather);
// partial dots combined via padded LDS. (2) k_logits_part streams fcW
// via block-staged, fully-coalesced nontemporal float4 bursts (per-
// thread math order unchanged -> bit-identical), grid 4096.

constexpr int F1  = 10;   // layer-1 width
constexpr int F1P = 16;   // layer-1 width padded (wave-friendly)
constexpr int HD  = 64;   // hidden width
constexpr int NC  = 10;   // classes
constexpr int LOGIT_BLOCKS = 4096;

constexpr int BSH   = 7;     // bucket = 128 dst nodes
constexpr int NBC   = 391;   // ceil(50000/128)  (compile-time LDS sizing)
constexpr int BCAPG = 5120;  // global region cap/bucket (mean 4096, +16 sigma)
constexpr int CSTR  = 16;    // cursor stride: one per 64B line
constexpr int LCAP  = 38;    // LDS stage cap/bucket (tile mean 21, +3.7 sigma)
constexpr int TILE  = 8192;  // edges per k_bucket block (512 thr x 16)

using f32x4 = __attribute__((ext_vector_type(4))) float;

static __device__ __forceinline__ float lrelu(float v) {
    return v > 0.0f ? v : 0.01f * v;
}

// fp8 e4m3 decode: hardware builtin if present, else header fallback
#if defined(__has_builtin)
#if __has_builtin(__builtin_amdgcn_cvt_f32_fp8)
#define FP8_DECODE(w, c) __builtin_amdgcn_cvt_f32_fp8((int)(w), (c))
#endif
#endif
#ifndef FP8_DECODE
static __device__ __forceinline__ float fp8_decode_sw(unsigned w, int c) {
    __hip_fp8_e4m3 t; t.__x = (unsigned char)(w >> (8 * c)); return (float)t;
}
#define FP8_DECODE(w, c) fp8_decode_sw((w), (c))
#endif

static __device__ __forceinline__ unsigned char fp8_encode(float v) {
    __hip_fp8_e4m3 t(v);
    return (unsigned char)t.__x;
}

// ---------- CSR build ----------
__global__ void k_bcur(int* __restrict__ bcur, int NB) {
    int b = blockIdx.x * blockDim.x + threadIdx.x;
    if (b < NB) bcur[b * CSTR] = b * BCAPG;
}

// pass 1: LDS-staged binning, wave-coalesced flush
__global__ __launch_bounds__(512) void k_bucket(const int* __restrict__ src,
                                                const int* __restrict__ dst,
                                                int* __restrict__ bcur,
                                                unsigned* __restrict__ bpairs, int E) {
    __shared__ unsigned stage[NBC * LCAP];   // 59.4 KB
    __shared__ int lcnt[NBC];
    for (int i = threadIdx.x; i < NBC; i += 512) lcnt[i] = 0;
    __syncthreads();
    int tile0 = blockIdx.x * TILE;
#pragma unroll
    for (int k = 0; k < TILE / 512; ++k) {
        int e = tile0 + k * 512 + threadIdx.x;
        if (e < E) {
            int d = dst[e];
            unsigned pk = (unsigned)src[e] | ((unsigned)(d & 127) << 16);
            int bb = d >> BSH;
            int pos = atomicAdd(&lcnt[bb], 1);
            if (pos < LCAP) stage[bb * LCAP + pos] = pk;
            else {                                   // rare spill (+3.7 sigma)
                int gp = atomicAdd(&bcur[bb * CSTR], 1);
                bpairs[gp] = pk;
            }
        }
    }
    __syncthreads();
    int wid = threadIdx.x >> 6, lane = threadIdx.x & 63;
    for (int bb = wid; bb < NBC; bb += 8) {
        int cntb = min(lcnt[bb], LCAP);
        if (cntb == 0) continue;
        int gp = 0;
        if (lane == 0) gp = atomicAdd(&bcur[bb * CSTR], cntb);
        gp = __shfl(gp, 0, 64);
        for (int i = lane; i < cntb; i += 64) bpairs[gp + i] = stage[bb * LCAP + i];
    }
}

// pass 2: per bucket: LDS histogram -> scan -> dinv/xs/rowbeg/rowend,
// counting sort -> coalesced uint16 CSR (bucket-padded layout)
__global__ __launch_bounds__(256) void k_fine(const int* __restrict__ bcur,
                                              const unsigned* __restrict__ bpairs,
                                              const float* __restrict__ x,
                                              unsigned short* __restrict__ csr,
                                              float* __restrict__ dinv,
                                              float* __restrict__ xs,
                                              int* __restrict__ rowbeg,
                                              int* __restrict__ rowend, int N) {
    __shared__ unsigned short lout[BCAPG];   // 10 KB
    __shared__ int lcnt[128], lbeg[128];
    int b = blockIdx.x;
    int n0 = b << BSH;
    int nn = min(128, N - n0);
    int base = b * BCAPG;
    int nedges = bcur[b * CSTR] - base;
    for (int i = threadIdx.x; i < nn; i += 256) lcnt[i] = 0;
    __syncthreads();
    for (int i = threadIdx.x; i < nedges; i += 256)
        atomicAdd(&lcnt[(bpairs[base + i] >> 16) & 127], 1);
    __syncthreads();
    if (threadIdx.x == 0) {
        int acc = 0;
        for (int j = 0; j < nn; ++j) { lbeg[j] = acc; acc += lcnt[j]; }
    }
    __syncthreads();
    for (int i = threadIdx.x; i < nn; i += 256) {
        int node = n0 + i;
        float di = rsqrtf(1.0f + (float)lcnt[i]);   // +1 self-loop
        dinv[node]   = di;
        xs[node]     = x[node] * di;
        rowbeg[node] = base + lbeg[i];
        rowend[node] = base + lbeg[i] + lcnt[i];
    }
    __syncthreads();
    for (int i = threadIdx.x; i < nn; i += 256) lcnt[i] = lbeg[i];
    __syncthreads();
    for (int i = threadIdx.x; i < nedges; i += 256) {
        unsigned p = bpairs[base + i];
        int pos = atomicAdd(&lcnt[(p >> 16) & 127], 1);
        lout[pos] = (unsigned short)(p & 0xFFFFu);
    }
    __syncthreads();
    for (int i = threadIdx.x; i < nedges; i += 256) csr[base + i] = lout[i];
}

// ---------- layer 1 fused: gather xs -> h1s = lrelu(s*W1+b1)*dinv (f16) ----------
__global__ void k_l1h1(const int* __restrict__ rowbeg, const int* __restrict__ rowend,
                       const unsigned short* __restrict__ csr,
                       const float* __restrict__ xs, const float* __restrict__ dinv,
                       const float* __restrict__ W1, const float* __restrict__ b1,
                       __half* __restrict__ h1s, int N) {
    int node = (blockIdx.x * blockDim.x + threadIdx.x) >> 6;
    int lane = threadIdx.x & 63;
    if (node >= N) return;
    int lo = rowbeg[node], hi = rowend[node];
    float acc = 0.0f;
    for (int j = lo + lane; j < hi; j += 64) acc += xs[csr[j]];
#pragma unroll
    for (int off = 32; off > 0; off >>= 1) acc += __shfl_xor(acc, off, 64);
    float di = dinv[node];
    float s = di * (acc + xs[node]);           // self-term folded
    if (lane < F1P) {
        float h = (lane < F1) ? lrelu(s * W1[lane] + b1[lane]) * di : 0.0f;
        h1s[node * F1P + lane] = __float2half(h);
    }
}

// ---------- layer 2 fused: wave/node, 8 edges/iter (half2), reg-W2 + LDS-broadcast dot ----------
// lane l: group g=l>>3 owns edge j+g, f2=l&7 owns feature pair 2*f2,2*f2+1
__global__ __launch_bounds__(256, 4) void k_l2h2(const int* __restrict__ rowbeg,
                                                 const int* __restrict__ rowend,
                                                 const unsigned short* __restrict__ csr,
                                                 const __half* __restrict__ h1s,
                                                 const float* __restrict__ dinv,
                                                 const float* __restrict__ W2,
                                                 const float* __restrict__ b2,
                                                 unsigned char* __restrict__ h2s8, int N) {
    __shared__ float awork[4][12];           // per-wave aggregate A[0..9] (+pad)
    int node = (blockIdx.x * blockDim.x + threadIdx.x) >> 6;
    int wid  = threadIdx.x >> 6;
    int lane = threadIdx.x & 63;
    bool valid = node < N;
    // prefetch W2 column (used only at the dot; hides under gather)
    float w2r[F1];
#pragma unroll
    for (int k = 0; k < F1; ++k) w2r[k] = W2[k * HD + lane];
    int g = lane >> 3, f2 = lane & 7;
    int lo = 0, deg = 0;
    if (valid) { lo = rowbeg[node]; deg = rowend[node] - lo; }
    int myidx = (lane < deg) ? (int)csr[lo + lane] : 0;   // whole row, 1 load
    int nfull = min(deg, 64);
    float a0 = 0.0f, a1 = 0.0f;
#pragma unroll
    for (int j = 0; j < 64; j += 8) {
        if (j >= nfull) break;                 // wave-uniform: skip dead iters
        int e = j + g;
        int sn = __shfl(myidx, e, 64);         // register-only broadcast
        if (e < nfull) {
            __half2 hv = *reinterpret_cast<const __half2*>(h1s + sn * F1P + f2 * 2);
            a0 += __low2float(hv);
            a1 += __high2float(hv);
        }
    }
    for (int j = 64; j < deg; j += 8) {        // tail: deg>64 (not for this graph)
        int e = j + g;
        if (e < deg) {
            int sn = csr[lo + e];
            __half2 hv = *reinterpret_cast<const __half2*>(h1s + sn * F1P + f2 * 2);
            a0 += __low2float(hv);
            a1 += __high2float(hv);
        }
    }
    // reduce across the 8 edge-groups (xor 8,16,32)
    a0 += __shfl_xor(a0, 8, 64); a0 += __shfl_xor(a0, 16, 64); a0 += __shfl_xor(a0, 32, 64);
    a1 += __shfl_xor(a1, 8, 64); a1 += __shfl_xor(a1, 16, 64); a1 += __shfl_xor(a1, 32, 64);
    // self-term
    if (valid) {
        __half2 hs = *reinterpret_cast<const __half2*>(h1s + node * F1P + f2 * 2);
        a0 += __low2float(hs);
        a1 += __high2float(hs);
    }
    if (g == 0 && f2 < 5)                      // lanes 0..4 hold A[0..9]
        *reinterpret_cast<float2*>(&awork[wid][f2 * 2]) = make_float2(a0, a1);
    __syncthreads();
    float4 av0 = *reinterpret_cast<const float4*>(&awork[wid][0]);
    float4 av1 = *reinterpret_cast<const float4*>(&awork[wid][4]);
    float2 av2 = *reinterpret_cast<const float2*>(&awork[wid][8]);
    float S = av0.x * w2r[0] + av0.y * w2r[1] + av0.z * w2r[2] + av0.w * w2r[3]
            + av1.x * w2r[4] + av1.y * w2r[5] + av1.z * w2r[6] + av1.w * w2r[7]
            + av2.x * w2r[8] + av2.y * w2r[9];
    if (valid) {
        float di = dinv[node];
        h2s8[node * HD + lane] = fp8_encode(lrelu(di * S + b2[lane]) * di);
    }
}

// ---------- layer 3 fused: wave/node gather (fp8 uchar4) + k-sharded W3 dot ----------
// Gather: lane l: group g=l>>4 owns edge j+g, q=l&15 owns features q*4..q*4+3.
// Dot: wave w holds W3 rows [16w,16w+16) (16 regs/lane) and computes 16-k
// partial dots for ALL 4 nodes; partials combined via padded LDS.
__global__ __launch_bounds__(256, 8) void k_l3h3(const int* __restrict__ rowbeg,
                                                 const int* __restrict__ rowend,
                                                 const unsigned short* __restrict__ csr,
                                                 const unsigned char* __restrict__ h2s8,
                                                 const float* __restrict__ dinv,
                                                 const float* __restrict__ W3,
                                                 const float* __restrict__ b3,
                                                 float* __restrict__ h3, int N) {
    __shared__ float awork[4][HD];           // per-wave aggregate A[0..63]
    __shared__ float plds[64][20];           // partial dots [lane][n*4+w], pad 20
    int node = (blockIdx.x * blockDim.x + threadIdx.x) >> 6;
    int wid  = threadIdx.x >> 6;
    int lane = threadIdx.x & 63;
    bool valid = node < N;
    // W3 shard: rows [16*wid, 16*wid+16), column `lane` (16 coalesced loads,
    // L2-hit; issued early, latency overlaps the gather)
    float w3r[16];
#pragma unroll
    for (int j = 0; j < 16; ++j) w3r[j] = W3[(16 * wid + j) * HD + lane];
    int g = lane >> 4, q = lane & 15;
    int lo = 0, deg = 0;
    if (valid) { lo = rowbeg[node]; deg = rowend[node] - lo; }
    int myidx = (lane < deg) ? (int)csr[lo + lane] : 0;   // whole row, 1 load
    int nfull = min(deg, 64);
    float a0 = 0.0f, a1 = 0.0f, a2 = 0.0f, a3 = 0.0f;
#pragma unroll
    for (int j = 0; j < 64; j += 4) {
        if (j >= nfull) break;                 // wave-uniform: skip dead iters
        int e = j + g;
        int sn = __shfl(myidx, e, 64);         // register-only broadcast
        if (e < nfull) {
            unsigned wv = *reinterpret_cast<const unsigned*>(h2s8 + sn * HD + q * 4);
            a0 += FP8_DECODE(wv, 0);
            a1 += FP8_DECODE(wv, 1);
            a2 += FP8_DECODE(wv, 2);
            a3 += FP8_DECODE(wv, 3);
        }
    }
    for (int j = 64; j < deg; j += 4) {        // tail: deg>64 (not for this graph)
        int e = j + g;
        if (e < deg) {
            int sn = csr[lo + e];
            unsigned wv = *reinterpret_cast<const unsigned*>(h2s8 + sn * HD + q * 4);
            a0 += FP8_DECODE(wv, 0);
            a1 += FP8_DECODE(wv, 1);
            a2 += FP8_DECODE(wv, 2);
            a3 += FP8_DECODE(wv, 3);
        }
    }
    // reduce across the 4 edge-groups (lanes q, q+16, q+32, q+48)
    a0 += __shfl_xor(a0, 16, 64); a0 += __shfl_xor(a0, 32, 64);
    a1 += __shfl_xor(a1, 16, 64); a1 += __shfl_xor(a1, 32, 64);
    a2 += __shfl_xor(a2, 16, 64); a2 += __shfl_xor(a2, 32, 64);
    a3 += __shfl_xor(a3, 16, 64); a3 += __shfl_xor(a3, 32, 64);
    // self-term (identical on all dup lanes)
    if (valid) {
        unsigned ws = *reinterpret_cast<const unsigned*>(h2s8 + node * HD + q * 4);
        a0 += FP8_DECODE(ws, 0);
        a1 += FP8_DECODE(ws, 1);
        a2 += FP8_DECODE(ws, 2);
        a3 += FP8_DECODE(ws, 3);
    }
    if (g == 0)                                // 16 lanes write the 64-float A row
        *reinterpret_cast<float4*>(&awork[wid][q * 4]) = make_float4(a0, a1, a2, a3);
    __syncthreads();
    // wave wid: partial dot over k in [16*wid,16*wid+16) for each node n
#pragma unroll
    for (int n = 0; n < 4; ++n) {
        float p = 0.0f;
#pragma unroll
        for (int jj = 0; jj < 4; ++jj) {       // broadcast b128 reads
            float4 av = *reinterpret_cast<const float4*>(&awork[n][16 * wid + 4 * jj]);
            p += av.x * w3r[4 * jj]     + av.y * w3r[4 * jj + 1]
               + av.z * w3r[4 * jj + 2] + av.w * w3r[4 * jj + 3];
        }
        plds[lane][n * 4 + wid] = p;
    }
    __syncthreads();
    if (valid) {
        float4 pv = *reinterpret_cast<const float4*>(&plds[lane][wid * 4]);
        float S = (pv.x + pv.y) + (pv.z + pv.w);
        float di = dinv[node];
        h3[node * HD + lane] = lrelu(di * S + b3[lane]);
    }
}

// ---------- FC partial: block-staged coalesced nt stream; 2 rows/thread ----------
__global__ __launch_bounds__(256) void k_logits_part(const float* __restrict__ h3,
                                                     const f32x4* __restrict__ fw4,
                                                     float* __restrict__ partial,
                                                     int P /*row pairs*/) {
    __shared__ f32x4 stage[1280];   // 256 pairs x 5 float4 = 20KB
    float acc[NC];
#pragma unroll
    for (int c = 0; c < NC; ++c) acc[c] = 0.0f;
    for (int pbase = blockIdx.x * 256; pbase < P; pbase += gridDim.x * 256) {
        int nfl = min(256, P - pbase) * 5;
        __syncthreads();                        // protect stage reuse
        for (int i = threadIdx.x; i < nfl; i += 256)
            stage[i] = __builtin_nontemporal_load(&fw4[(size_t)pbase * 5 + i]);
        __syncthreads();
        int p = pbase + threadIdx.x;
        if (p < P) {
            const f32x4* w = &stage[threadIdx.x * 5];
            f32x4 w0 = w[0], w1 = w[1], w2 = w[2], w3 = w[3], w4 = w[4];
            float2 hv = *reinterpret_cast<const float2*>(h3 + 2 * (size_t)p);
            acc[0] += hv.x * w0.x; acc[1] += hv.x * w0.y; acc[2] += hv.x * w0.z; acc[3] += hv.x * w0.w;
            acc[4] += hv.x * w1.x; acc[5] += hv.x * w1.y; acc[6] += hv.x * w1.z; acc[7] += hv.x * w1.w;
            acc[8] += hv.x * w2.x; acc[9] += hv.x * w2.y; acc[0] += hv.y * w2.z; acc[1] += hv.y * w2.w;
            acc[2] += hv.y * w3.x; acc[3] += hv.y * w3.y; acc[4] += hv.y * w3.z; acc[5] += hv.y * w3.w;
            acc[6] += hv.y * w4.x; acc[7] += hv.y * w4.y; acc[8] += hv.y * w4.z; acc[9] += hv.y * w4.w;
        }
    }
#pragma unroll
    for (int c = 0; c < NC; ++c) {
        float v = acc[c];
#pragma unroll
        for (int off = 32; off > 0; off >>= 1) v += __shfl_down(v, off, 64);
        acc[c] = v;
    }
    __shared__ float ls[4][NC];
    int wid = threadIdx.x >> 6, lane = threadIdx.x & 63;
    if (lane == 0) {
#pragma unroll
        for (int c = 0; c < NC; ++c) ls[wid][c] = acc[c];
    }
    __syncthreads();
    if (threadIdx.x < NC) {
        float ssum = ls[0][threadIdx.x] + ls[1][threadIdx.x]
                   + ls[2][threadIdx.x] + ls[3][threadIdx.x];
        partial[blockIdx.x * NC + threadIdx.x] = ssum;
    }
}

// reduce per-block partials + bias + softmax, single block (1024 thr)
__global__ __launch_bounds__(1024) void k_final(const float* __restrict__ partial, int nblk,
                                                const float* __restrict__ fcb,
                                                float* __restrict__ out) {
    __shared__ float ls[NC];
    if (threadIdx.x < NC) ls[threadIdx.x] = 0.0f;
    __syncthreads();
    const int NCHUNK = 1024 / NC;            // 102 stripes per class
    int c = threadIdx.x % NC;
    int chunk = threadIdx.x / NC;
    float ssum = 0.0f;
    if (chunk < NCHUNK)
        for (int i = chunk; i < nblk; i += NCHUNK) ssum += partial[i * NC + c];
    if (chunk < NCHUNK) atomicAdd(&ls[c], ssum);
    __syncthreads();
    if (threadIdx.x == 0) {
        float l[NC], m = -1e30f;
        for (int k = 0; k < NC; ++k) { l[k] = ls[k] + fcb[k]; m = fmaxf(m, l[k]); }
        float sum = 0.0f;
        for (int k = 0; k < NC; ++k) { l[k] = expf(l[k] - m); sum += l[k]; }
        float inv = 1.0f / sum;
        for (int k = 0; k < NC; ++k) out[k] = l[k] * inv;
    }
}

extern "C" void kernel_launch(void* const* d_in, const int* in_sizes, int n_in,
                              void* d_out, int out_size, void* d_ws, size_t ws_size,
                              hipStream_t stream) {
    const float* x   = (const float*)d_in[0];
    const int*   ei  = (const int*)d_in[1];
    const float* W1  = (const float*)d_in[2];
    const float* b1  = (const float*)d_in[3];
    const float* W2  = (const float*)d_in[4];
    const float* b2  = (const float*)d_in[5];
    const float* W3  = (const float*)d_in[6];
    const float* b3  = (const float*)d_in[7];
    const float* fcW = (const float*)d_in[8];
    const float* fcb = (const float*)d_in[9];
    float* out = (float*)d_out;

    const int N = in_sizes[0];           // 50000
    const int E = in_sizes[1] / 2;       // 1600000
    const int* src = ei;
    const int* dst = ei + E;
    const int NB = (N + 127) >> BSH;     // 391 buckets

    // workspace carve-up (4B units)
    char* w = (char*)d_ws;
    auto take = [&](size_t elems) { void* p = w; w += elems * 4; return p; };
    float* dinv    = (float*)take(N);
    int*   rowbeg  = (int*)  take(N);
    int*   rowend  = (int*)  take(N);
    int*   bcur    = (int*)  take((size_t)NB * CSTR);
    unsigned short* csr = (unsigned short*)take((size_t)NB * BCAPG / 2); // u16, padded
    float* xs      = (float*)take(N);          // scaled input; FC partials later
    __half* h1s    = (__half*)take((size_t)N * F1P / 2);  // f16, h1*dinv
    unsigned char* h2s8 = (unsigned char*)take((size_t)N * HD / 4);  // fp8, h2*dinv
    float* h3      = (float*)take((size_t)N * HD);
    float* partial = xs;                        // xs dead after k_l1h1 (40960 < N)
    unsigned* bpairs = (unsigned*)h3;           // h3 not live during CSR build (8MB<12.8MB)

    const int B = 256;
    auto cdiv = [](long long a, long long b) { return (int)((a + b - 1) / b); };

    // CSR build
    k_bcur  <<<cdiv(NB, B), B, 0, stream>>>(bcur, NB);
    k_bucket<<<cdiv(E, TILE), 512, 0, stream>>>(src, dst, bcur, bpairs, E);
    k_fine  <<<NB, 256, 0, stream>>>(bcur, bpairs, x, csr, dinv, xs, rowbeg, rowend, N);

    // fused layers
    k_l1h1<<<cdiv((long long)N * 64, B), B, 0, stream>>>(rowbeg, rowend, csr, xs, dinv, W1, b1, h1s, N);
    k_l2h2<<<cdiv((long long)N * 64, B), B, 0, stream>>>(rowbeg, rowend, csr, h1s, dinv, W2, b2, h2s8, N);
    k_l3h3<<<cdiv((long long)N * 64, B), B, 0, stream>>>(rowbeg, rowend, csr, h2s8, dinv, W3, b3, h3, N);

    // FC + softmax
    const int P = (N * HD) / 2;
    k_logits_part<<<LOGIT_BLOCKS, B, 0, stream>>>(h3, (const f32x4*)fcW, partial, P);
    k_final<<<1, 1024, 0, stream>>>(partial, LOGIT_BLOCKS, fcb, out);
}